// Round 1
// baseline (682.392 us; speedup 1.0000x reference)
//
#include <hip/hip_runtime.h>

#define E_DIM 512
#define N_DIM 512
#define B_DIM 32
#define H_DIM 8
#define D_DIM 8
#define P3    192   // 3 * H * D

// ---------------------------------------------------------------------------
// K0a: Wt[e][p'] = W_which[p][e] * g_which[e]   (fold LN gamma, transpose)
// p' = which*64 + p, layout Wt[E][192] so GEMM lane reads are coalesced.
// ---------------------------------------------------------------------------
__global__ void prep_wt(const float* __restrict__ Wq, const float* __restrict__ Wk,
                        const float* __restrict__ Wv,
                        const float* __restrict__ gq, const float* __restrict__ gk,
                        const float* __restrict__ gv,
                        float* __restrict__ Wt) {
    int e  = blockIdx.x;     // 512
    int pp = threadIdx.x;    // 192
    int which = pp >> 6, p = pp & 63;
    const float* W = (which == 0) ? Wq : (which == 1) ? Wk : Wv;
    const float* g = (which == 0) ? gq : (which == 1) ? gk : gv;
    Wt[e * P3 + pp] = W[p * E_DIM + e] * g[e];
}

// ---------------------------------------------------------------------------
// K0b: b2[p'] = proj_bias[p] + dot(W_which[p,:], ln_beta_which)
// ---------------------------------------------------------------------------
__global__ void prep_b2(const float* __restrict__ Wq, const float* __restrict__ Wk,
                        const float* __restrict__ Wv,
                        const float* __restrict__ bnq, const float* __restrict__ bnk,
                        const float* __restrict__ bnv,
                        const float* __restrict__ bq, const float* __restrict__ bk,
                        const float* __restrict__ bv,
                        float* __restrict__ b2) {
    int pp = threadIdx.x;    // 192, one block
    int which = pp >> 6, p = pp & 63;
    const float* W  = (which == 0) ? Wq  : (which == 1) ? Wk  : Wv;
    const float* bn = (which == 0) ? bnq : (which == 1) ? bnk : bnv;
    const float* bb = (which == 0) ? bq  : (which == 1) ? bk  : bv;
    float s = bb[p];
    for (int e = 0; e < E_DIM; ++e) s += W[p * E_DIM + e] * bn[e];
    b2[pp] = s;
}

// ---------------------------------------------------------------------------
// K3: Wl2_t[(h*512+n)*8+d] = sum_e Wl[n*512+e] * Wo[e*64 + h*8 + d]
// ---------------------------------------------------------------------------
__global__ __launch_bounds__(256) void prep_wl2(const float* __restrict__ Wl,
                                                const float* __restrict__ Wo,
                                                float* __restrict__ Wl2) {
    int idx = blockIdx.x * 256 + threadIdx.x;   // 0..32767
    int d = idx & 7, n = (idx >> 3) & 511, h = idx >> 12;
    int p = h * 8 + d;
    float s = 0.f;
    for (int e = 0; e < E_DIM; ++e) s += Wl[n * E_DIM + e] * Wo[e * 64 + p];
    Wl2[idx] = s;
}

__device__ inline float block_reduce_256(float v) {
    __shared__ float red[4];
    #pragma unroll
    for (int m = 32; m >= 1; m >>= 1) v += __shfl_xor(v, m);
    int w = threadIdx.x >> 6;
    if ((threadIdx.x & 63) == 0) red[w] = v;
    __syncthreads();
    if (threadIdx.x == 0) v = red[0] + red[1] + red[2] + red[3];
    return v;
}

// K3b: c0 = bl + sum_f bo[f&511] * Wl[f]
__global__ __launch_bounds__(256) void prep_c0(const float* __restrict__ Wl,
                                               const float* __restrict__ bo,
                                               const float* __restrict__ bl,
                                               float* __restrict__ c0) {
    float s = 0.f;
    for (int f = threadIdx.x; f < N_DIM * E_DIM; f += 256) s += Wl[f] * bo[f & 511];
    s = block_reduce_256(s);
    if (threadIdx.x == 0) c0[0] = s + bl[0];
}

// ---------------------------------------------------------------------------
// K1: fused LayerNorm + QKV projection.
// Block = 256 threads, 16 rows of x. Phase A: LN (16 lanes/row).
// Phase B: GEMM 16x512 @ 512x192, thread = (tx in 0..63, rowgroup rg in 0..3),
// computes 4 rows x 3 outputs. xhat reads are wave-uniform LDS broadcasts,
// Wt reads are lane-coalesced (64 consecutive floats).
// Output layout: q/k/v as [B][H][N][8] so attention loads are contiguous.
// ---------------------------------------------------------------------------
__global__ __launch_bounds__(256) void ln_qkv(const float* __restrict__ x,
                                              const float* __restrict__ Wt,
                                              const float* __restrict__ b2,
                                              float* __restrict__ qkv) {
    __shared__ float xh[16 * E_DIM];
    const int t = threadIdx.x;
    const int row0 = blockIdx.x * 16;
    // ---- Phase A: LayerNorm 16 rows ----
    {
        int r = t >> 4, sub = t & 15;
        const float4* xr = (const float4*)(x + (size_t)(row0 + r) * E_DIM + sub * 32);
        float4 v[8];
        float s = 0.f, sq = 0.f;
        #pragma unroll
        for (int l = 0; l < 8; ++l) {
            v[l] = xr[l];
            s  += v[l].x + v[l].y + v[l].z + v[l].w;
            sq += v[l].x * v[l].x + v[l].y * v[l].y + v[l].z * v[l].z + v[l].w * v[l].w;
        }
        #pragma unroll
        for (int m = 8; m >= 1; m >>= 1) { s += __shfl_xor(s, m); sq += __shfl_xor(sq, m); }
        float mean = s * (1.f / E_DIM);
        float var  = sq * (1.f / E_DIM) - mean * mean;
        float rs   = rsqrtf(var + 1e-5f);
        float4* dst = (float4*)(xh + r * E_DIM + sub * 32);
        #pragma unroll
        for (int l = 0; l < 8; ++l) {
            float4 o;
            o.x = (v[l].x - mean) * rs; o.y = (v[l].y - mean) * rs;
            o.z = (v[l].z - mean) * rs; o.w = (v[l].w - mean) * rs;
            dst[l] = o;
        }
    }
    __syncthreads();
    // ---- Phase B: GEMM ----
    const int tx = t & 63, rg = t >> 6;
    float acc[4][3];
    {
        float b0 = b2[tx], b1 = b2[tx + 64], b1b = b2[tx + 128];
        #pragma unroll
        for (int k = 0; k < 4; ++k) { acc[k][0] = b0; acc[k][1] = b1; acc[k][2] = b1b; }
    }
    #pragma unroll 2
    for (int e = 0; e < E_DIM; ++e) {
        float w0 = Wt[e * P3 + tx];
        float w1 = Wt[e * P3 + tx + 64];
        float w2 = Wt[e * P3 + tx + 128];
        #pragma unroll
        for (int k = 0; k < 4; ++k) {
            float xv = xh[(rg + 4 * k) * E_DIM + e];
            acc[k][0] += xv * w0;
            acc[k][1] += xv * w1;
            acc[k][2] += xv * w2;
        }
    }
    const size_t BHN8 = (size_t)B_DIM * H_DIM * N_DIM * D_DIM;
    const int h = tx >> 3, d = tx & 7;
    #pragma unroll
    for (int k = 0; k < 4; ++k) {
        int ng = row0 + rg + 4 * k;
        int b = ng >> 9, n = ng & 511;
        size_t base = (((size_t)(b * H_DIM + h)) * N_DIM + n) * D_DIM + d;
        qkv[base]            = acc[k][0];
        qkv[BHN8 + base]     = acc[k][1];
        qkv[2 * BHN8 + base] = acc[k][2];
    }
}

// ---------------------------------------------------------------------------
// K2: iterative Hopfield retrieval. One block = (b,h, half of rows).
// K and V for (b,h) staged in LDS (16 KB each); every lane walks the same j,
// so LDS reads are same-address broadcasts (conflict-free).
// 3 iterations against K, final association against V. Writes o over q.
// ---------------------------------------------------------------------------
__global__ __launch_bounds__(256) void hopfield(float* __restrict__ q,
                                                const float* __restrict__ k,
                                                const float* __restrict__ v) {
    __shared__ float Kl[N_DIM * D_DIM];
    __shared__ float Vl[N_DIM * D_DIM];
    const int t = threadIdx.x;
    const int bh = blockIdx.x >> 1, half = blockIdx.x & 1;
    {
        const float4* ks = (const float4*)(k + (size_t)bh * N_DIM * D_DIM);
        const float4* vs = (const float4*)(v + (size_t)bh * N_DIM * D_DIM);
        #pragma unroll
        for (int l = 0; l < 4; ++l) {
            ((float4*)Kl)[l * 256 + t] = ks[l * 256 + t];
            ((float4*)Vl)[l * 256 + t] = vs[l * 256 + t];
        }
    }
    __syncthreads();
    const int i = half * 256 + t;
    float* qrow = q + ((size_t)bh * N_DIM + i) * D_DIM;
    float4 xa = ((const float4*)qrow)[0];
    float4 xb = ((const float4*)qrow)[1];

    for (int it = 0; it < 3; ++it) {
        float l = 0.f;
        float4 aa = {0, 0, 0, 0}, ab = {0, 0, 0, 0};
        #pragma unroll 4
        for (int j = 0; j < N_DIM; ++j) {
            float4 ka = ((const float4*)Kl)[2 * j];
            float4 kb = ((const float4*)Kl)[2 * j + 1];
            float s = xa.x * ka.x + xa.y * ka.y + xa.z * ka.z + xa.w * ka.w
                    + xb.x * kb.x + xb.y * kb.y + xb.z * kb.z + xb.w * kb.w;
            float ee = __expf(0.25f * s);
            l += ee;
            aa.x += ee * ka.x; aa.y += ee * ka.y; aa.z += ee * ka.z; aa.w += ee * ka.w;
            ab.x += ee * kb.x; ab.y += ee * kb.y; ab.z += ee * kb.z; ab.w += ee * kb.w;
        }
        float inv = 1.f / l;
        xa.x = aa.x * inv; xa.y = aa.y * inv; xa.z = aa.z * inv; xa.w = aa.w * inv;
        xb.x = ab.x * inv; xb.y = ab.y * inv; xb.z = ab.z * inv; xb.w = ab.w * inv;
    }
    // final association with V (scores still vs K)
    {
        float l = 0.f;
        float4 aa = {0, 0, 0, 0}, ab = {0, 0, 0, 0};
        #pragma unroll 4
        for (int j = 0; j < N_DIM; ++j) {
            float4 ka = ((const float4*)Kl)[2 * j];
            float4 kb = ((const float4*)Kl)[2 * j + 1];
            float s = xa.x * ka.x + xa.y * ka.y + xa.z * ka.z + xa.w * ka.w
                    + xb.x * kb.x + xb.y * kb.y + xb.z * kb.z + xb.w * kb.w;
            float ee = __expf(0.25f * s);
            l += ee;
            float4 va = ((const float4*)Vl)[2 * j];
            float4 vb = ((const float4*)Vl)[2 * j + 1];
            aa.x += ee * va.x; aa.y += ee * va.y; aa.z += ee * va.z; aa.w += ee * va.w;
            ab.x += ee * vb.x; ab.y += ee * vb.y; ab.z += ee * vb.z; ab.w += ee * vb.w;
        }
        float inv = 1.f / l;
        float4 oa, ob;
        oa.x = aa.x * inv; oa.y = aa.y * inv; oa.z = aa.z * inv; oa.w = aa.w * inv;
        ob.x = ab.x * inv; ob.y = ab.y * inv; ob.z = ab.z * inv; ob.w = ab.w * inv;
        ((float4*)qrow)[0] = oa;
        ((float4*)qrow)[1] = ob;
    }
}

// ---------------------------------------------------------------------------
// K4: y[b] = c0 + dot(o_flat[b], Wl2)   (32768-elem dot per batch)
// ---------------------------------------------------------------------------
__global__ __launch_bounds__(256) void finalize(const float* __restrict__ o,
                                                const float* __restrict__ Wl2,
                                                const float* __restrict__ c0,
                                                float* __restrict__ y) {
    const int b = blockIdx.x;
    const float* ob = o + (size_t)b * (H_DIM * N_DIM * D_DIM);
    float s = 0.f;
    for (int f = threadIdx.x; f < H_DIM * N_DIM * D_DIM; f += 256) s += ob[f] * Wl2[f];
    s = block_reduce_256(s);
    if (threadIdx.x == 0) y[b] = s + c0[0];
}

// ---------------------------------------------------------------------------
extern "C" void kernel_launch(void* const* d_in, const int* in_sizes, int n_in,
                              void* d_out, int out_size, void* d_ws, size_t ws_size,
                              hipStream_t stream) {
    const float* x   = (const float*)d_in[0];
    const float* g_q = (const float*)d_in[1];
    const float* b_q = (const float*)d_in[2];
    const float* g_k = (const float*)d_in[3];
    const float* b_k = (const float*)d_in[4];
    const float* g_v = (const float*)d_in[5];
    const float* b_v = (const float*)d_in[6];
    const float* Wq  = (const float*)d_in[7];
    const float* bq  = (const float*)d_in[8];
    const float* Wk  = (const float*)d_in[9];
    const float* bk  = (const float*)d_in[10];
    const float* Wv  = (const float*)d_in[11];
    const float* bv  = (const float*)d_in[12];
    const float* Wo  = (const float*)d_in[13];
    const float* bo  = (const float*)d_in[14];
    const float* Wl  = (const float*)d_in[15];
    const float* bl  = (const float*)d_in[16];
    float* out = (float*)d_out;

    float* ws = (float*)d_ws;
    // workspace layout (float offsets), all 16B-aligned
    float* Wt   = ws;                       // 512*192 = 98304
    float* b2   = ws + 98304;               // 192
    float* c0   = ws + 98496;               // 1 (+pad)
    float* Wl2  = ws + 98560;               // 32768
    float* q_t  = ws + 131584;              // 1048576   [B][H][N][8]
    float* k_t  = q_t + 1048576;
    float* v_t  = k_t + 1048576;

    prep_wt <<<512, 192, 0, stream>>>(Wq, Wk, Wv, g_q, g_k, g_v, Wt);
    prep_b2 <<<1, 192, 0, stream>>>(Wq, Wk, Wv, b_q, b_k, b_v, bq, bk, bv, b2);
    prep_wl2<<<128, 256, 0, stream>>>(Wl, Wo, Wl2);
    prep_c0 <<<1, 256, 0, stream>>>(Wl, bo, bl, c0);
    ln_qkv  <<<1024, 256, 0, stream>>>(x, Wt, b2, q_t);
    hopfield<<<512, 256, 0, stream>>>(q_t, k_t, v_t);
    finalize<<<32, 256, 0, stream>>>(q_t, Wl2, c0, out);
}

// Round 2
// 427.938 us; speedup vs baseline: 1.5946x; 1.5946x over previous
//
#include <hip/hip_runtime.h>

#define E_DIM 512
#define N_DIM 512
#define B_DIM 32
#define H_DIM 8
#define D_DIM 8
#define P3    192   // 3 * H * D

// ---------------------------------------------------------------------------
// K0a: Wt[e][p'] = W_which[p][e] * g_which[e]   (fold LN gamma, transpose)
// One block per p' (192 blocks): coalesced read of W row, strided write.
// ---------------------------------------------------------------------------
__global__ __launch_bounds__(256) void prep_wt(const float* __restrict__ Wq,
                        const float* __restrict__ Wk, const float* __restrict__ Wv,
                        const float* __restrict__ gq, const float* __restrict__ gk,
                        const float* __restrict__ gv,
                        float* __restrict__ Wt) {
    int pp = blockIdx.x;     // 192
    int which = pp >> 6, p = pp & 63;
    const float* W = (which == 0) ? Wq : (which == 1) ? Wk : Wv;
    const float* g = (which == 0) ? gq : (which == 1) ? gk : gv;
    int t = threadIdx.x;
    #pragma unroll
    for (int l = 0; l < 2; ++l) {
        int e = t + l * 256;
        Wt[e * P3 + pp] = W[p * E_DIM + e] * g[e];
    }
}

__device__ inline float block_reduce_256(float v) {
    __shared__ float red[4];
    #pragma unroll
    for (int m = 32; m >= 1; m >>= 1) v += __shfl_xor(v, m);
    int w = threadIdx.x >> 6;
    if ((threadIdx.x & 63) == 0) red[w] = v;
    __syncthreads();
    if (threadIdx.x == 0) v = red[0] + red[1] + red[2] + red[3];
    return v;
}

// ---------------------------------------------------------------------------
// K0b: b2[p'] = proj_bias[p] + dot(W_which[p,:], ln_beta_which)
// One block per p' (192 blocks), coalesced reads + block reduce.
// ---------------------------------------------------------------------------
__global__ __launch_bounds__(256) void prep_b2(const float* __restrict__ Wq,
                        const float* __restrict__ Wk, const float* __restrict__ Wv,
                        const float* __restrict__ bnq, const float* __restrict__ bnk,
                        const float* __restrict__ bnv,
                        const float* __restrict__ bq, const float* __restrict__ bk,
                        const float* __restrict__ bv,
                        float* __restrict__ b2) {
    int pp = blockIdx.x;     // 192
    int which = pp >> 6, p = pp & 63;
    const float* W  = (which == 0) ? Wq  : (which == 1) ? Wk  : Wv;
    const float* bn = (which == 0) ? bnq : (which == 1) ? bnk : bnv;
    const float* bb = (which == 0) ? bq  : (which == 1) ? bk  : bv;
    int t = threadIdx.x;
    float s = W[p * E_DIM + t] * bn[t] + W[p * E_DIM + t + 256] * bn[t + 256];
    s = block_reduce_256(s);
    if (t == 0) b2[pp] = s + bb[p];
}

// ---------------------------------------------------------------------------
// K3: Wl2[h*4096 + n*8 + d] = sum_e Wl[n*512+e] * Wo[e*64 + h*8 + d]
// One block per n (512 blocks, 64 threads): Wl row in LDS (broadcast reads),
// Wo reads lane-coalesced (64 consecutive floats per e).
// ---------------------------------------------------------------------------
__global__ __launch_bounds__(64) void prep_wl2(const float* __restrict__ Wl,
                                               const float* __restrict__ Wo,
                                               float* __restrict__ Wl2) {
    __shared__ float row[E_DIM];
    int n = blockIdx.x, t = threadIdx.x;
    #pragma unroll
    for (int l = 0; l < 8; ++l) row[t + l * 64] = Wl[n * E_DIM + t + l * 64];
    __syncthreads();
    float s = 0.f;
    #pragma unroll 4
    for (int e = 0; e < E_DIM; ++e) s += row[e] * Wo[e * 64 + t];
    Wl2[(t >> 3) * (N_DIM * D_DIM) + n * D_DIM + (t & 7)] = s;
}

// ---------------------------------------------------------------------------
// K3b: partials[blk] = partial sum of bo[f&511] * Wl[f]  (64 blocks)
// finalize folds partials + bl into its reduction.
// ---------------------------------------------------------------------------
__global__ __launch_bounds__(256) void prep_c0(const float* __restrict__ Wl,
                                               const float* __restrict__ bo,
                                               float* __restrict__ partials) {
    int f0 = blockIdx.x * 4096 + threadIdx.x;
    float s = 0.f;
    #pragma unroll
    for (int l = 0; l < 16; ++l) {
        int f = f0 + l * 256;
        s += Wl[f] * bo[f & 511];
    }
    s = block_reduce_256(s);
    if (threadIdx.x == 0) partials[blockIdx.x] = s;
}

// ---------------------------------------------------------------------------
// K1: fused LayerNorm + QKV projection.
// Block = 256 threads, 16 rows of x. Phase A: LN (16 lanes/row).
// Phase B: GEMM 16x512 @ 512x192; xhat reads are wave-uniform LDS broadcasts,
// Wt reads are lane-coalesced. Output layout q/k/v: [B][H][N][8].
// ---------------------------------------------------------------------------
__global__ __launch_bounds__(256) void ln_qkv(const float* __restrict__ x,
                                              const float* __restrict__ Wt,
                                              const float* __restrict__ b2,
                                              float* __restrict__ qkv) {
    __shared__ float xh[16 * E_DIM];
    const int t = threadIdx.x;
    const int row0 = blockIdx.x * 16;
    {
        int r = t >> 4, sub = t & 15;
        const float4* xr = (const float4*)(x + (size_t)(row0 + r) * E_DIM + sub * 32);
        float4 v[8];
        float s = 0.f, sq = 0.f;
        #pragma unroll
        for (int l = 0; l < 8; ++l) {
            v[l] = xr[l];
            s  += v[l].x + v[l].y + v[l].z + v[l].w;
            sq += v[l].x * v[l].x + v[l].y * v[l].y + v[l].z * v[l].z + v[l].w * v[l].w;
        }
        #pragma unroll
        for (int m = 8; m >= 1; m >>= 1) { s += __shfl_xor(s, m); sq += __shfl_xor(sq, m); }
        float mean = s * (1.f / E_DIM);
        float var  = sq * (1.f / E_DIM) - mean * mean;
        float rs   = rsqrtf(var + 1e-5f);
        float4* dst = (float4*)(xh + r * E_DIM + sub * 32);
        #pragma unroll
        for (int l = 0; l < 8; ++l) {
            float4 o;
            o.x = (v[l].x - mean) * rs; o.y = (v[l].y - mean) * rs;
            o.z = (v[l].z - mean) * rs; o.w = (v[l].w - mean) * rs;
            dst[l] = o;
        }
    }
    __syncthreads();
    const int tx = t & 63, rg = t >> 6;
    float acc[4][3];
    {
        float b0 = b2[tx], b1 = b2[tx + 64], b1b = b2[tx + 128];
        #pragma unroll
        for (int k = 0; k < 4; ++k) { acc[k][0] = b0; acc[k][1] = b1; acc[k][2] = b1b; }
    }
    #pragma unroll 2
    for (int e = 0; e < E_DIM; ++e) {
        float w0 = Wt[e * P3 + tx];
        float w1 = Wt[e * P3 + tx + 64];
        float w2 = Wt[e * P3 + tx + 128];
        #pragma unroll
        for (int k = 0; k < 4; ++k) {
            float xv = xh[(rg + 4 * k) * E_DIM + e];
            acc[k][0] += xv * w0;
            acc[k][1] += xv * w1;
            acc[k][2] += xv * w2;
        }
    }
    const size_t BHN8 = (size_t)B_DIM * H_DIM * N_DIM * D_DIM;
    const int h = tx >> 3, d = tx & 7;
    #pragma unroll
    for (int k = 0; k < 4; ++k) {
        int ng = row0 + rg + 4 * k;
        int b = ng >> 9, n = ng & 511;
        size_t base = (((size_t)(b * H_DIM + h)) * N_DIM + n) * D_DIM + d;
        qkv[base]            = acc[k][0];
        qkv[BHN8 + base]     = acc[k][1];
        qkv[2 * BHN8 + base] = acc[k][2];
    }
}

// ---------------------------------------------------------------------------
// K2: iterative Hopfield retrieval. One block = (b,h, half of rows).
// K,V staged in LDS; all lanes walk the same j -> broadcast reads.
// ---------------------------------------------------------------------------
__global__ __launch_bounds__(256) void hopfield(float* __restrict__ q,
                                                const float* __restrict__ k,
                                                const float* __restrict__ v) {
    __shared__ float Kl[N_DIM * D_DIM];
    __shared__ float Vl[N_DIM * D_DIM];
    const int t = threadIdx.x;
    const int bh = blockIdx.x >> 1, half = blockIdx.x & 1;
    {
        const float4* ks = (const float4*)(k + (size_t)bh * N_DIM * D_DIM);
        const float4* vs = (const float4*)(v + (size_t)bh * N_DIM * D_DIM);
        #pragma unroll
        for (int l = 0; l < 4; ++l) {
            ((float4*)Kl)[l * 256 + t] = ks[l * 256 + t];
            ((float4*)Vl)[l * 256 + t] = vs[l * 256 + t];
        }
    }
    __syncthreads();
    const int i = half * 256 + t;
    float* qrow = q + ((size_t)bh * N_DIM + i) * D_DIM;
    float4 xa = ((const float4*)qrow)[0];
    float4 xb = ((const float4*)qrow)[1];

    for (int it = 0; it < 3; ++it) {
        float l = 0.f;
        float4 aa = {0, 0, 0, 0}, ab = {0, 0, 0, 0};
        #pragma unroll 4
        for (int j = 0; j < N_DIM; ++j) {
            float4 ka = ((const float4*)Kl)[2 * j];
            float4 kb = ((const float4*)Kl)[2 * j + 1];
            float s = xa.x * ka.x + xa.y * ka.y + xa.z * ka.z + xa.w * ka.w
                    + xb.x * kb.x + xb.y * kb.y + xb.z * kb.z + xb.w * kb.w;
            float ee = __expf(0.25f * s);
            l += ee;
            aa.x += ee * ka.x; aa.y += ee * ka.y; aa.z += ee * ka.z; aa.w += ee * ka.w;
            ab.x += ee * kb.x; ab.y += ee * kb.y; ab.z += ee * kb.z; ab.w += ee * kb.w;
        }
        float inv = 1.f / l;
        xa.x = aa.x * inv; xa.y = aa.y * inv; xa.z = aa.z * inv; xa.w = aa.w * inv;
        xb.x = ab.x * inv; xb.y = ab.y * inv; xb.z = ab.z * inv; xb.w = ab.w * inv;
    }
    {
        float l = 0.f;
        float4 aa = {0, 0, 0, 0}, ab = {0, 0, 0, 0};
        #pragma unroll 4
        for (int j = 0; j < N_DIM; ++j) {
            float4 ka = ((const float4*)Kl)[2 * j];
            float4 kb = ((const float4*)Kl)[2 * j + 1];
            float s = xa.x * ka.x + xa.y * ka.y + xa.z * ka.z + xa.w * ka.w
                    + xb.x * kb.x + xb.y * kb.y + xb.z * kb.z + xb.w * kb.w;
            float ee = __expf(0.25f * s);
            l += ee;
            float4 va = ((const float4*)Vl)[2 * j];
            float4 vb = ((const float4*)Vl)[2 * j + 1];
            aa.x += ee * va.x; aa.y += ee * va.y; aa.z += ee * va.z; aa.w += ee * va.w;
            ab.x += ee * vb.x; ab.y += ee * vb.y; ab.z += ee * vb.z; ab.w += ee * vb.w;
        }
        float inv = 1.f / l;
        float4 oa, ob;
        oa.x = aa.x * inv; oa.y = aa.y * inv; oa.z = aa.z * inv; oa.w = aa.w * inv;
        ob.x = ab.x * inv; ob.y = ab.y * inv; ob.z = ab.z * inv; ob.w = ab.w * inv;
        ((float4*)qrow)[0] = oa;
        ((float4*)qrow)[1] = ob;
    }
}

// ---------------------------------------------------------------------------
// K4: y[b] = bl + sum(partials) + dot(o_flat[b], Wl2)
// ---------------------------------------------------------------------------
__global__ __launch_bounds__(256) void finalize(const float* __restrict__ o,
                                                const float* __restrict__ Wl2,
                                                const float* __restrict__ partials,
                                                const float* __restrict__ bl,
                                                float* __restrict__ y) {
    const int b = blockIdx.x;
    const float* ob = o + (size_t)b * (H_DIM * N_DIM * D_DIM);
    float s = 0.f;
    for (int f = threadIdx.x; f < H_DIM * N_DIM * D_DIM; f += 256) s += ob[f] * Wl2[f];
    if (threadIdx.x < 64) s += partials[threadIdx.x];
    s = block_reduce_256(s);
    if (threadIdx.x == 0) y[b] = s + bl[0];
}

// ---------------------------------------------------------------------------
extern "C" void kernel_launch(void* const* d_in, const int* in_sizes, int n_in,
                              void* d_out, int out_size, void* d_ws, size_t ws_size,
                              hipStream_t stream) {
    const float* x   = (const float*)d_in[0];
    const float* g_q = (const float*)d_in[1];
    const float* b_q = (const float*)d_in[2];
    const float* g_k = (const float*)d_in[3];
    const float* b_k = (const float*)d_in[4];
    const float* g_v = (const float*)d_in[5];
    const float* b_v = (const float*)d_in[6];
    const float* Wq  = (const float*)d_in[7];
    const float* bq  = (const float*)d_in[8];
    const float* Wk  = (const float*)d_in[9];
    const float* bk  = (const float*)d_in[10];
    const float* Wv  = (const float*)d_in[11];
    const float* bv  = (const float*)d_in[12];
    const float* Wo  = (const float*)d_in[13];
    const float* bo  = (const float*)d_in[14];
    const float* Wl  = (const float*)d_in[15];
    const float* bl  = (const float*)d_in[16];
    float* out = (float*)d_out;

    float* ws = (float*)d_ws;
    float* Wt       = ws;                   // 512*192 = 98304
    float* b2       = ws + 98304;           // 192
    float* partials = ws + 98496;           // 64
    float* Wl2      = ws + 98560;           // 32768
    float* q_t      = ws + 131584;          // 1048576   [B][H][N][8]
    float* k_t      = q_t + 1048576;
    float* v_t      = k_t + 1048576;

    prep_wt <<<192, 256, 0, stream>>>(Wq, Wk, Wv, g_q, g_k, g_v, Wt);
    prep_b2 <<<192, 256, 0, stream>>>(Wq, Wk, Wv, b_q, b_k, b_v, bq, bk, bv, b2);
    prep_wl2<<<512, 64, 0, stream>>>(Wl, Wo, Wl2);
    prep_c0 <<<64, 256, 0, stream>>>(Wl, bo, partials);
    ln_qkv  <<<1024, 256, 0, stream>>>(x, Wt, b2, q_t);
    hopfield<<<512, 256, 0, stream>>>(q_t, k_t, v_t);
    finalize<<<32, 256, 0, stream>>>(q_t, Wl2, partials, bl, out);
}